// Round 1
// baseline (121.126 us; speedup 1.0000x reference)
//
#include <hip/hip_runtime.h>
#include <math.h>

#define BATCH 64
#define DK 256
#define FEATURES 512
#define NUM_TAPE 2048
#define TOPK 512
#define THRESH 4.0f
#define KCHUNKS 8
#define KPER (TOPK / KCHUNKS) /* 64 */

// output layout (floats)
#define OFF_Q 0
#define OFF_HP (BATCH * DK)                    /* 16384 */
#define OFF_REM (OFF_HP + BATCH)               /* 16448 */
#define OFF_NUP (OFF_REM + BATCH)              /* 16512 */
#define OFF_MASK (OFF_NUP + BATCH)             /* 16576 */
#define OFF_TSEL (OFF_MASK + BATCH * NUM_TAPE) /* 147648 */

// ws layout (floats)
#define WS_SCORES 0                       /* 64*2048 = 131072 */
#define WS_TOPK 131072                    /* int, 64*512 */
#define WS_WEIGHTS 163840                 /* 64*512 */
#define WS_PART 196608                    /* 64*8*512 = 262144 */

// ---------------- Kernel A: scores[b][n] = dot(q[b,:256], tape[b,n,:256]) ----------
__global__ __launch_bounds__(256) void k_scores(const float* __restrict__ q,
                                                const float* __restrict__ tape,
                                                float* __restrict__ scores) {
    const int b = blockIdx.y;
    const int wave = threadIdx.x >> 6;
    const int lane = threadIdx.x & 63;
    // 64 lanes x float4 = 256 floats = the key slice
    const float4 qf = reinterpret_cast<const float4*>(q + b * DK)[lane];
    const int base = blockIdx.x * 32;
#pragma unroll
    for (int t = 0; t < 8; ++t) {
        const int tok = base + wave + 4 * t;
        const float4 tf =
            reinterpret_cast<const float4*>(tape + ((size_t)b * NUM_TAPE + tok) * FEATURES)[lane];
        float s = qf.x * tf.x + qf.y * tf.y + qf.z * tf.z + qf.w * tf.w;
#pragma unroll
        for (int off = 32; off; off >>= 1) s += __shfl_xor(s, off);
        if (lane == 0) scores[b * NUM_TAPE + tok] = s;
    }
}

// ---------------- Kernel B: per-batch sort + softmax + scalars + mask ----------------
__global__ __launch_bounds__(256) void k_topk(const float* __restrict__ scores,
                                              const float* __restrict__ mask_in,
                                              const float* __restrict__ hp_in,
                                              const float* __restrict__ rem_in,
                                              const float* __restrict__ nup_in,
                                              int* __restrict__ topk_ws,
                                              float* __restrict__ weights_ws,
                                              float* __restrict__ out) {
    const int b = blockIdx.x;
    const int tid = threadIdx.x;
    __shared__ float sv[NUM_TAPE];
    __shared__ int si[NUM_TAPE];
    __shared__ float red[256];

    for (int n = tid; n < NUM_TAPE; n += 256) {
        sv[n] = scores[b * NUM_TAPE + n] - mask_in[b * NUM_TAPE + n] * 1e9f;
        si[n] = n;
    }
    __syncthreads();

    // bitonic sort, descending by value; ties -> smaller original index first
    for (int k = 2; k <= NUM_TAPE; k <<= 1) {
        for (int j = k >> 1; j > 0; j >>= 1) {
            for (int i = tid; i < NUM_TAPE; i += 256) {
                const int ixj = i ^ j;
                if (ixj > i) {
                    float a = sv[i], c = sv[ixj];
                    int ai = si[i], ci = si[ixj];
                    // ib: d[i] belongs before d[ixj] in DESCENDING order
                    bool ib = (a > c) || (a == c && ai < ci);
                    bool doswap = ((i & k) == 0) ? (!ib) : ib;
                    if (doswap) {
                        sv[i] = c; sv[ixj] = a;
                        si[i] = ci; si[ixj] = ai;
                    }
                }
            }
            __syncthreads();
        }
    }

    // top-512 indices; gather weights from ROW 0 scores (jnp.take flatten bug)
    for (int kk = tid; kk < TOPK; kk += 256) {
        const int idx = si[kk];
        topk_ws[b * TOPK + kk] = idx;
        sv[kk] = scores[idx] * 0.0625f; // scores[0, idx] / sqrt(256)
    }
    __syncthreads();

    // max over sv[0..511]
    float m = -1e30f;
    for (int kk = tid; kk < TOPK; kk += 256) m = fmaxf(m, sv[kk]);
    red[tid] = m;
    __syncthreads();
    for (int s = 128; s; s >>= 1) {
        if (tid < s) red[tid] = fmaxf(red[tid], red[tid + s]);
        __syncthreads();
    }
    const float mmax = red[0];
    __syncthreads();

    // exp & sum
    float lsum = 0.f;
    for (int kk = tid; kk < TOPK; kk += 256) {
        float w = expf(sv[kk] - mmax);
        sv[kk] = w;
        lsum += w;
    }
    red[tid] = lsum;
    __syncthreads();
    for (int s = 128; s; s >>= 1) {
        if (tid < s) red[tid] += red[tid + s];
        __syncthreads();
    }
    const float inv = 1.0f / red[0];
    __syncthreads();

    // normalize, write weights, sum of squares
    float lsq = 0.f;
    for (int kk = tid; kk < TOPK; kk += 256) {
        float w = sv[kk] * inv;
        sv[kk] = w;
        weights_ws[b * TOPK + kk] = w;
        lsq += w * w;
    }
    red[tid] = lsq;
    __syncthreads();
    for (int s = 128; s; s >>= 1) {
        if (tid < s) red[tid] += red[tid + s];
        __syncthreads();
    }
    const float sumsq = red[0];
    __syncthreads();

    if (tid == 0) {
        float hp = hp_in[b], rem = rem_in[b], nup = nup_in[b];
        float entropy = 1.0f - sumsq;
        float s16 = 0.f;
        for (int i = 0; i < 16; ++i) s16 += sv[i];
        float still = (hp < THRESH) ? 1.f : 0.f;
        float nh = ((hp + s16) >= THRESH ? 1.f : 0.f) * still;
        float st2 = still - nh;
        out[OFF_REM + b] = rem + (nh + st2) * entropy;
        float hp1 = hp + s16 * st2;
        hp1 = hp1 + nh * (THRESH - hp1);
        out[OFF_HP + b] = hp1;
        out[OFF_NUP + b] = nup + st2 + nh;
    }

    // score_mask out = in, then +1 at selected (indices are distinct)
    for (int n = tid; n < NUM_TAPE; n += 256)
        out[OFF_MASK + b * NUM_TAPE + n] = mask_in[b * NUM_TAPE + n];
    __syncthreads();
    for (int kk = tid; kk < TOPK; kk += 256) {
        const int idx = si[kk];
        out[OFF_MASK + b * NUM_TAPE + idx] = mask_in[b * NUM_TAPE + idx] + 1.0f;
    }
}

// ---------------- Kernel C: partial weighted sums over k-chunks ----------------
__global__ __launch_bounds__(512) void k_gather(const float* __restrict__ tape,
                                                const int* __restrict__ topk_ws,
                                                const float* __restrict__ weights_ws,
                                                float* __restrict__ partials) {
    const int b = blockIdx.y;
    const int kc = blockIdx.x;
    const int f = threadIdx.x;
    __shared__ float wsh[KPER];
    __shared__ int ish[KPER];
    if (f < KPER) {
        wsh[f] = weights_ws[b * TOPK + kc * KPER + f];
        ish[f] = topk_ws[b * TOPK + kc * KPER + f];
    }
    __syncthreads();
    float acc = 0.f;
#pragma unroll 4
    for (int k = 0; k < KPER; ++k) {
        acc = fmaf(wsh[k], tape[((size_t)b * NUM_TAPE + ish[k]) * FEATURES + f], acc);
    }
    partials[((size_t)b * KCHUNKS + kc) * FEATURES + f] = acc;
}

// ---------------- Kernel D: reduce partials -> token_sel + query update ------------
__global__ __launch_bounds__(512) void k_finish(const float* __restrict__ q,
                                                const float* __restrict__ partials,
                                                float* __restrict__ out) {
    const int b = blockIdx.x;
    const int f = threadIdx.x;
    float s = 0.f;
#pragma unroll
    for (int kc = 0; kc < KCHUNKS; ++kc) s += partials[((size_t)b * KCHUNKS + kc) * FEATURES + f];
    out[OFF_TSEL + b * FEATURES + f] = s;
    if (f < DK) out[OFF_Q + b * DK + f] = (q[b * DK + f] + s) * 0.5f;
}

extern "C" void kernel_launch(void* const* d_in, const int* in_sizes, int n_in,
                              void* d_out, int out_size, void* d_ws, size_t ws_size,
                              hipStream_t stream) {
    const float* q = (const float*)d_in[0];
    const float* hp = (const float*)d_in[1];
    const float* rem = (const float*)d_in[2];
    const float* nup = (const float*)d_in[3];
    const float* mask = (const float*)d_in[4];
    const float* tape = (const float*)d_in[5];
    float* out = (float*)d_out;
    float* ws = (float*)d_ws;

    float* scores = ws + WS_SCORES;
    int* topk = (int*)(ws + WS_TOPK);
    float* weights = ws + WS_WEIGHTS;
    float* partials = ws + WS_PART;

    k_scores<<<dim3(NUM_TAPE / 32, BATCH), 256, 0, stream>>>(q, tape, scores);
    k_topk<<<BATCH, 256, 0, stream>>>(scores, mask, hp, rem, nup, topk, weights, out);
    k_gather<<<dim3(KCHUNKS, BATCH), 512, 0, stream>>>(tape, topk, weights, partials);
    k_finish<<<BATCH, 512, 0, stream>>>(q, partials, out);
}

// Round 2
// 55.994 us; speedup vs baseline: 2.1632x; 2.1632x over previous
//
#include <hip/hip_runtime.h>
#include <math.h>

#define BATCH 64
#define DK 256
#define FEATURES 512
#define NUM_TAPE 2048
#define TOPK 512
#define TOP16 16
#define THRESH 4.0f
#define KCHUNKS 8
#define KPER (TOPK / KCHUNKS) /* 64 */
#define TIECAP 640

// output layout (floats)
#define OFF_Q 0
#define OFF_HP (BATCH * DK)                    /* 16384 */
#define OFF_REM (OFF_HP + BATCH)               /* 16448 */
#define OFF_NUP (OFF_REM + BATCH)              /* 16512 */
#define OFF_MASK (OFF_NUP + BATCH)             /* 16576 */
#define OFF_TSEL (OFF_MASK + BATCH * NUM_TAPE) /* 147648 */

// ws layout (floats)
#define WS_SCORES 0      /* 64*2048 */
#define WS_TOPK 131072   /* int, 64*512 */
#define WS_WEIGHTS 163840
#define WS_PART 196608 /* 64*8*512 */

__device__ __forceinline__ unsigned f2key(float f) {
    unsigned u = __float_as_uint(f);
    return (u & 0x80000000u) ? ~u : (u | 0x80000000u);
}

// ---------------- Kernel A: scores[b][n] = dot(q[b,:256], tape[b,n,:256]) ----------
__global__ __launch_bounds__(256) void k_scores(const float* __restrict__ q,
                                                const float* __restrict__ tape,
                                                float* __restrict__ scores) {
    const int b = blockIdx.y;
    const int wave = threadIdx.x >> 6;
    const int lane = threadIdx.x & 63;
    const float4 qf = reinterpret_cast<const float4*>(q + b * DK)[lane];
    const int base = blockIdx.x * 32;
#pragma unroll
    for (int t = 0; t < 8; ++t) {
        const int tok = base + wave + 4 * t;
        const float4 tf =
            reinterpret_cast<const float4*>(tape + ((size_t)b * NUM_TAPE + tok) * FEATURES)[lane];
        float s = qf.x * tf.x + qf.y * tf.y + qf.z * tf.z + qf.w * tf.w;
#pragma unroll
        for (int off = 32; off; off >>= 1) s += __shfl_xor(s, off);
        if (lane == 0) scores[b * NUM_TAPE + tok] = s;
    }
}

// ---------------- Kernel B: per-batch radix-select top-k + softmax + scalars --------
__global__ __launch_bounds__(256) void k_topk(const float* __restrict__ scores,
                                              const float* __restrict__ mask_in,
                                              const float* __restrict__ hp_in,
                                              const float* __restrict__ rem_in,
                                              const float* __restrict__ nup_in,
                                              int* __restrict__ topk_ws,
                                              float* __restrict__ weights_ws,
                                              float* __restrict__ out) {
    const int b = blockIdx.x;
    const int tid = threadIdx.x;
    __shared__ int hist[256];
    __shared__ int sh_digit, sh_hi;
    __shared__ int sel_idx[TOPK];
    __shared__ unsigned sel_key[TOPK];
    __shared__ float sel_w[TOPK];
    __shared__ float red[256];
    __shared__ int tie_idx[TIECAP];
    __shared__ int tie_cnt, sel_cnt;
    __shared__ int in16_idx[TOP16];

    // load scores for this row into registers as sortable keys
    unsigned key[8];
#pragma unroll
    for (int i = 0; i < 8; ++i) {
        const int e = i * 256 + tid;
        const float v = scores[b * NUM_TAPE + e] - mask_in[b * NUM_TAPE + e] * 1e9f;
        key[i] = f2key(v);
    }

    // two radix selects: kth-largest key for k=TOPK and k=TOP16
    unsigned T512 = 0, T16 = 0;
    int krem512 = 0, krem16 = 0;
    for (int sel = 0; sel < 2; ++sel) {
        const int k = sel ? TOP16 : TOPK;
        unsigned prefix = 0;
        int krem = k;
        for (int p = 0; p < 4; ++p) {
            const int shift = 24 - 8 * p;
            hist[tid] = 0;
            __syncthreads();
#pragma unroll
            for (int i = 0; i < 8; ++i) {
                const unsigned kk = key[i];
                const bool act = (p == 0) || ((kk >> (shift + 8)) == (prefix >> (shift + 8)));
                if (act) atomicAdd(&hist[(kk >> shift) & 0xFF], 1);
            }
            __syncthreads();
            // suffix-inclusive scan (Hillis-Steele, in place)
            for (int off = 1; off < 256; off <<= 1) {
                const int v = (tid + off < 256) ? hist[tid + off] : 0;
                __syncthreads();
                hist[tid] += v;
                __syncthreads();
            }
            const int sv = hist[tid];
            const int nxt = (tid < 255) ? hist[tid + 1] : 0;
            if (sv >= krem && nxt < krem) {
                sh_digit = tid;
                sh_hi = nxt;
            }
            __syncthreads();
            prefix |= ((unsigned)sh_digit) << shift;
            krem -= sh_hi;
            __syncthreads();
        }
        if (sel == 0) {
            T512 = prefix;
            krem512 = krem;
        } else {
            T16 = prefix;
            krem16 = krem;
        }
    }

    // ---- build selected set: key > T512, plus first krem512 ties by ascending idx
    if (tid == 0) {
        sel_cnt = 0;
        tie_cnt = 0;
    }
    __syncthreads();
#pragma unroll
    for (int i = 0; i < 8; ++i) {
        const int e = i * 256 + tid;
        const unsigned kk = key[i];
        if (kk > T512) {
            const int p = atomicAdd(&sel_cnt, 1);
            sel_idx[p] = e;
            sel_key[p] = kk;
        } else if (kk == T512) {
            const int p = atomicAdd(&tie_cnt, 1);
            if (p < TIECAP) tie_idx[p] = e;
        }
    }
    __syncthreads();
    int tc = tie_cnt < TIECAP ? tie_cnt : TIECAP;
    for (int t = tid; t < tc; t += 256) {
        const int my = tie_idx[t];
        int rank = 0;
        for (int u = 0; u < tc; ++u) rank += (tie_idx[u] < my);
        if (rank < krem512) {
            const int p = atomicAdd(&sel_cnt, 1);
            sel_idx[p] = my;
            sel_key[p] = T512;
        }
    }
    __syncthreads();

    // ---- top16 tie list (for membership of the == T16 boundary element(s))
    if (tid == 0) tie_cnt = 0;
    __syncthreads();
#pragma unroll
    for (int i = 0; i < 8; ++i) {
        const int e = i * 256 + tid;
        if (key[i] == T16) {
            const int p = atomicAdd(&tie_cnt, 1);
            if (p < TIECAP) tie_idx[p] = e;
        }
    }
    __syncthreads();
    tc = tie_cnt < TIECAP ? tie_cnt : TIECAP;
    for (int t = tid; t < tc; t += 256) {
        const int my = tie_idx[t];
        int rank = 0;
        for (int u = 0; u < tc; ++u) rank += (tie_idx[u] < my);
        if (rank < krem16) in16_idx[rank] = my;
    }
    __syncthreads();

    // ---- softmax over row-0 scores at selected idx (jnp.take flatten semantics)
    float m = -1e30f;
    for (int s = tid; s < TOPK; s += 256) {
        const float w = scores[sel_idx[s]] * 0.0625f; // scores[0, idx] / sqrt(256)
        sel_w[s] = w;
        m = fmaxf(m, w);
    }
    red[tid] = m;
    __syncthreads();
    for (int s = 128; s; s >>= 1) {
        if (tid < s) red[tid] = fmaxf(red[tid], red[tid + s]);
        __syncthreads();
    }
    const float mmax = red[0];
    __syncthreads();

    float lsum = 0.f;
    for (int s = tid; s < TOPK; s += 256) {
        const float w = expf(sel_w[s] - mmax);
        sel_w[s] = w;
        lsum += w;
    }
    red[tid] = lsum;
    __syncthreads();
    for (int s = 128; s; s >>= 1) {
        if (tid < s) red[tid] += red[tid + s];
        __syncthreads();
    }
    const float inv = 1.0f / red[0];
    __syncthreads();

    float lsq = 0.f, l16 = 0.f;
    for (int s = tid; s < TOPK; s += 256) {
        const float w = sel_w[s] * inv;
        const int idx = sel_idx[s];
        weights_ws[b * TOPK + s] = w;
        topk_ws[b * TOPK + s] = idx;
        lsq += w * w;
        const unsigned kk = sel_key[s];
        bool in16 = (kk > T16);
        if (kk == T16) {
            for (int u = 0; u < krem16; ++u)
                if (in16_idx[u] == idx) in16 = true;
        }
        if (in16) l16 += w;
    }
    red[tid] = lsq;
    __syncthreads();
    for (int s = 128; s; s >>= 1) {
        if (tid < s) red[tid] += red[tid + s];
        __syncthreads();
    }
    const float sumsq = red[0];
    __syncthreads();
    red[tid] = l16;
    __syncthreads();
    for (int s = 128; s; s >>= 1) {
        if (tid < s) red[tid] += red[tid + s];
        __syncthreads();
    }
    const float s16 = red[0];
    __syncthreads();

    if (tid == 0) {
        const float hp = hp_in[b], rem = rem_in[b], nup = nup_in[b];
        const float entropy = 1.0f - sumsq;
        const float still = (hp < THRESH) ? 1.f : 0.f;
        const float nh = ((hp + s16) >= THRESH ? 1.f : 0.f) * still;
        const float st2 = still - nh;
        out[OFF_REM + b] = rem + (nh + st2) * entropy;
        float hp1 = hp + s16 * st2;
        hp1 = hp1 + nh * (THRESH - hp1);
        out[OFF_HP + b] = hp1;
        out[OFF_NUP + b] = nup + st2 + nh;
    }

    // score_mask out = in, then +1 at selected (indices distinct)
    for (int n = tid; n < NUM_TAPE; n += 256)
        out[OFF_MASK + b * NUM_TAPE + n] = mask_in[b * NUM_TAPE + n];
    __syncthreads();
    for (int s = tid; s < TOPK; s += 256) {
        const int idx = sel_idx[s];
        out[OFF_MASK + b * NUM_TAPE + idx] = mask_in[b * NUM_TAPE + idx] + 1.0f;
    }
}

// ---------------- Kernel C: partial weighted sums over k-chunks ----------------
__global__ __launch_bounds__(512) void k_gather(const float* __restrict__ tape,
                                                const int* __restrict__ topk_ws,
                                                const float* __restrict__ weights_ws,
                                                float* __restrict__ partials) {
    const int b = blockIdx.y;
    const int kc = blockIdx.x;
    const int f = threadIdx.x;
    __shared__ float wsh[KPER];
    __shared__ int ish[KPER];
    if (f < KPER) {
        wsh[f] = weights_ws[b * TOPK + kc * KPER + f];
        ish[f] = topk_ws[b * TOPK + kc * KPER + f];
    }
    __syncthreads();
    float acc = 0.f;
#pragma unroll 4
    for (int k = 0; k < KPER; ++k) {
        acc = fmaf(wsh[k], tape[((size_t)b * NUM_TAPE + ish[k]) * FEATURES + f], acc);
    }
    partials[((size_t)b * KCHUNKS + kc) * FEATURES + f] = acc;
}

// ---------------- Kernel D: reduce partials -> token_sel + query update ------------
__global__ __launch_bounds__(512) void k_finish(const float* __restrict__ q,
                                                const float* __restrict__ partials,
                                                float* __restrict__ out) {
    const int b = blockIdx.x;
    const int f = threadIdx.x;
    float s = 0.f;
#pragma unroll
    for (int kc = 0; kc < KCHUNKS; ++kc) s += partials[((size_t)b * KCHUNKS + kc) * FEATURES + f];
    out[OFF_TSEL + b * FEATURES + f] = s;
    if (f < DK) out[OFF_Q + b * DK + f] = (q[b * DK + f] + s) * 0.5f;
}

extern "C" void kernel_launch(void* const* d_in, const int* in_sizes, int n_in,
                              void* d_out, int out_size, void* d_ws, size_t ws_size,
                              hipStream_t stream) {
    const float* q = (const float*)d_in[0];
    const float* hp = (const float*)d_in[1];
    const float* rem = (const float*)d_in[2];
    const float* nup = (const float*)d_in[3];
    const float* mask = (const float*)d_in[4];
    const float* tape = (const float*)d_in[5];
    float* out = (float*)d_out;
    float* ws = (float*)d_ws;

    float* scores = ws + WS_SCORES;
    int* topk = (int*)(ws + WS_TOPK);
    float* weights = ws + WS_WEIGHTS;
    float* partials = ws + WS_PART;

    k_scores<<<dim3(NUM_TAPE / 32, BATCH), 256, 0, stream>>>(q, tape, scores);
    k_topk<<<BATCH, 256, 0, stream>>>(scores, mask, hp, rem, nup, topk, weights, out);
    k_gather<<<dim3(KCHUNKS, BATCH), 512, 0, stream>>>(tape, topk, weights, partials);
    k_finish<<<BATCH, 512, 0, stream>>>(q, partials, out);
}

// Round 3
// 50.855 us; speedup vs baseline: 2.3818x; 1.1011x over previous
//
#include <hip/hip_runtime.h>
#include <math.h>

#define BATCH 64
#define DK 256
#define FEATURES 512
#define NUM_TAPE 2048
#define TOPK 512
#define TOP16 16
#define THRESH 4.0f
#define KCHUNKS 8
#define KPER (TOPK / KCHUNKS) /* 64 */
#define TIECAP 640

// output layout (floats)
#define OFF_Q 0
#define OFF_HP (BATCH * DK)                    /* 16384 */
#define OFF_REM (OFF_HP + BATCH)               /* 16448 */
#define OFF_NUP (OFF_REM + BATCH)              /* 16512 */
#define OFF_MASK (OFF_NUP + BATCH)             /* 16576 */
#define OFF_TSEL (OFF_MASK + BATCH * NUM_TAPE) /* 147648 */

// ws layout (floats)
#define WS_SCORES 0      /* 64*2048 */
#define WS_TOPK 131072   /* int, 64*512 */
#define WS_WEIGHTS 163840
#define WS_PART 196608 /* 64*8*512 */

__device__ __forceinline__ unsigned f2key(float f) {
    unsigned u = __float_as_uint(f);
    return (u & 0x80000000u) ? ~u : (u | 0x80000000u);
}

// ---------------- Kernel A: scores[b][n] = dot(q[b,:256], tape[b,n,:256]) ----------
__global__ __launch_bounds__(256) void k_scores(const float* __restrict__ q,
                                                const float* __restrict__ tape,
                                                float* __restrict__ scores) {
    const int b = blockIdx.y;
    const int wave = threadIdx.x >> 6;
    const int lane = threadIdx.x & 63;
    const float4 qf = reinterpret_cast<const float4*>(q + b * DK)[lane];
    const int base = blockIdx.x * 32;
#pragma unroll
    for (int t = 0; t < 8; ++t) {
        const int tok = base + wave + 4 * t;
        const float4 tf =
            reinterpret_cast<const float4*>(tape + ((size_t)b * NUM_TAPE + tok) * FEATURES)[lane];
        float s = qf.x * tf.x + qf.y * tf.y + qf.z * tf.z + qf.w * tf.w;
#pragma unroll
        for (int off = 32; off; off >>= 1) s += __shfl_xor(s, off);
        if (lane == 0) scores[b * NUM_TAPE + tok] = s;
    }
}

// ---------------- Kernel B: per-batch radix-select top-k + softmax + scalars --------
__global__ __launch_bounds__(512) void k_topk(const float* __restrict__ scores,
                                              const float* __restrict__ mask_in,
                                              const float* __restrict__ hp_in,
                                              const float* __restrict__ rem_in,
                                              const float* __restrict__ nup_in,
                                              int* __restrict__ topk_ws,
                                              float* __restrict__ weights_ws,
                                              float* __restrict__ out) {
    const int b = blockIdx.x;
    const int tid = threadIdx.x;
    const int lane = tid & 63;
    const int wv = tid >> 6;
    __shared__ int hist[256];
    __shared__ int chunkTot[4];
    __shared__ int sh_digit, sh_hi;
    __shared__ int sel_idx[TOPK];
    __shared__ unsigned sel_key[TOPK];
    __shared__ float redf[8];
    __shared__ int tie_idx[TIECAP];
    __shared__ int tie_cnt, sel_cnt;
    __shared__ int in16_idx[TOP16];

    // 4 elements per thread, float4-coalesced: e = 4*tid + j
    const float4 sc = reinterpret_cast<const float4*>(scores + (size_t)b * NUM_TAPE)[tid];
    const float4 mk = reinterpret_cast<const float4*>(mask_in + (size_t)b * NUM_TAPE)[tid];
    unsigned key[4];
    key[0] = f2key(sc.x - mk.x * 1e9f);
    key[1] = f2key(sc.y - mk.y * 1e9f);
    key[2] = f2key(sc.z - mk.z * 1e9f);
    key[3] = f2key(sc.w - mk.w * 1e9f);

    // ---- radix select 1: k = 512 over 2048 keys
    unsigned prefix = 0;
    int krem = TOPK;
#pragma unroll
    for (int p = 0; p < 4; ++p) {
        const int shift = 24 - 8 * p;
        if (tid < 256) hist[tid] = 0;
        __syncthreads();
#pragma unroll
        for (int i = 0; i < 4; ++i) {
            const unsigned kk = key[i];
            const bool act = (p == 0) || ((kk >> (shift + 8)) == (prefix >> (shift + 8)));
            if (act) atomicAdd(&hist[(kk >> shift) & 0xFF], 1);
        }
        __syncthreads();
        int v = 0, hcnt = 0;
        if (tid < 256) {
            hcnt = hist[tid];
            v = hcnt;
#pragma unroll
            for (int off = 1; off < 64; off <<= 1) {
                const int t = __shfl_down(v, off);
                if (lane + off < 64) v += t;
            }
            if (lane == 0) chunkTot[wv] = v;
        }
        __syncthreads();
        if (tid < 256) {
#pragma unroll
            for (int w2 = 0; w2 < 4; ++w2)
                if (w2 > wv) v += chunkTot[w2];
            if (v >= krem && (v - hcnt) < krem) {
                sh_digit = tid;
                sh_hi = v - hcnt;
            }
        }
        __syncthreads();
        prefix |= ((unsigned)sh_digit) << shift;
        krem -= sh_hi;
        __syncthreads();
    }
    const unsigned T512 = prefix;
    const int krem512 = krem;

    // ---- compaction: key > T512 plus first krem512 ties (ascending index)
    if (tid == 0) {
        sel_cnt = 0;
        tie_cnt = 0;
    }
    __syncthreads();
#pragma unroll
    for (int i = 0; i < 4; ++i) {
        const int e = 4 * tid + i;
        const unsigned kk = key[i];
        if (kk > T512) {
            const int p = atomicAdd(&sel_cnt, 1);
            sel_idx[p] = e;
            sel_key[p] = kk;
        } else if (kk == T512) {
            const int p = atomicAdd(&tie_cnt, 1);
            if (p < TIECAP) tie_idx[p] = e;
        }
    }
    __syncthreads();
    int tc = tie_cnt < TIECAP ? tie_cnt : TIECAP;
    for (int t = tid; t < tc; t += 512) {
        const int my = tie_idx[t];
        int rank = 0;
        for (int u = 0; u < tc; ++u) rank += (tie_idx[u] < my);
        if (rank < krem512) {
            const int p = atomicAdd(&sel_cnt, 1);
            sel_idx[p] = my;
            sel_key[p] = T512;
        }
    }
    __syncthreads();

    // ---- radix select 2: k = 16 over the 512 selected keys (1/thread)
    const unsigned kk2 = sel_key[tid];
    prefix = 0;
    krem = TOP16;
#pragma unroll
    for (int p = 0; p < 4; ++p) {
        const int shift = 24 - 8 * p;
        if (tid < 256) hist[tid] = 0;
        __syncthreads();
        {
            const bool act = (p == 0) || ((kk2 >> (shift + 8)) == (prefix >> (shift + 8)));
            if (act) atomicAdd(&hist[(kk2 >> shift) & 0xFF], 1);
        }
        __syncthreads();
        int v = 0, hcnt = 0;
        if (tid < 256) {
            hcnt = hist[tid];
            v = hcnt;
#pragma unroll
            for (int off = 1; off < 64; off <<= 1) {
                const int t = __shfl_down(v, off);
                if (lane + off < 64) v += t;
            }
            if (lane == 0) chunkTot[wv] = v;
        }
        __syncthreads();
        if (tid < 256) {
#pragma unroll
            for (int w2 = 0; w2 < 4; ++w2)
                if (w2 > wv) v += chunkTot[w2];
            if (v >= krem && (v - hcnt) < krem) {
                sh_digit = tid;
                sh_hi = v - hcnt;
            }
        }
        __syncthreads();
        prefix |= ((unsigned)sh_digit) << shift;
        krem -= sh_hi;
        __syncthreads();
    }
    const unsigned T16 = prefix;
    const int krem16 = krem;

    // ---- top16 boundary-tie membership (ascending original index)
    if (tid == 0) tie_cnt = 0;
    __syncthreads();
    if (kk2 == T16) {
        const int p = atomicAdd(&tie_cnt, 1);
        if (p < TIECAP) tie_idx[p] = sel_idx[tid];
    }
    __syncthreads();
    tc = tie_cnt < TIECAP ? tie_cnt : TIECAP;
    for (int t = tid; t < tc; t += 512) {
        const int my = tie_idx[t];
        int rank = 0;
        for (int u = 0; u < tc; ++u) rank += (tie_idx[u] < my);
        if (rank < krem16) in16_idx[rank] = my;
    }
    __syncthreads();

    // ---- softmax over row-0 scores at selected idx (jnp.take flatten semantics)
    const int myidx = sel_idx[tid];
    const float wraw = scores[myidx] * 0.0625f; // scores[0, idx] / sqrt(256)

    // block max
    float m = wraw;
#pragma unroll
    for (int off = 32; off; off >>= 1) m = fmaxf(m, __shfl_xor(m, off));
    if (lane == 0) redf[wv] = m;
    __syncthreads();
#pragma unroll
    for (int w2 = 0; w2 < 8; ++w2) m = fmaxf(m, redf[w2]);
    __syncthreads();

    const float e = expf(wraw - m);
    float s = e;
#pragma unroll
    for (int off = 32; off; off >>= 1) s += __shfl_xor(s, off);
    if (lane == 0) redf[wv] = s;
    __syncthreads();
    s = 0.f;
#pragma unroll
    for (int w2 = 0; w2 < 8; ++w2) s += redf[w2];
    __syncthreads();

    const float w = e / s;
    weights_ws[b * TOPK + tid] = w;
    topk_ws[b * TOPK + tid] = myidx;

    float lsq = w * w;
#pragma unroll
    for (int off = 32; off; off >>= 1) lsq += __shfl_xor(lsq, off);
    if (lane == 0) redf[wv] = lsq;
    __syncthreads();
    float sumsq = 0.f;
#pragma unroll
    for (int w2 = 0; w2 < 8; ++w2) sumsq += redf[w2];
    __syncthreads();

    bool in16 = (kk2 > T16);
    if (kk2 == T16) {
        for (int u = 0; u < krem16; ++u)
            if (in16_idx[u] == myidx) in16 = true;
    }
    float l16 = in16 ? w : 0.f;
#pragma unroll
    for (int off = 32; off; off >>= 1) l16 += __shfl_xor(l16, off);
    if (lane == 0) redf[wv] = l16;
    __syncthreads();
    float s16 = 0.f;
#pragma unroll
    for (int w2 = 0; w2 < 8; ++w2) s16 += redf[w2];

    if (tid == 0) {
        const float hp = hp_in[b], rem = rem_in[b], nup = nup_in[b];
        const float entropy = 1.0f - sumsq;
        const float still = (hp < THRESH) ? 1.f : 0.f;
        const float nh = ((hp + s16) >= THRESH ? 1.f : 0.f) * still;
        const float st2 = still - nh;
        out[OFF_REM + b] = rem + (nh + st2) * entropy;
        float hp1 = hp + s16 * st2;
        hp1 = hp1 + nh * (THRESH - hp1);
        out[OFF_HP + b] = hp1;
        out[OFF_NUP + b] = nup + st2 + nh;
    }

    // score_mask: copy row (we already hold it as mk), then +1 at selected
    reinterpret_cast<float4*>(out + OFF_MASK + (size_t)b * NUM_TAPE)[tid] = mk;
    __syncthreads();
    out[OFF_MASK + b * NUM_TAPE + myidx] = mask_in[b * NUM_TAPE + myidx] + 1.0f;
}

// ---------------- Kernel C: partial weighted sums over k-chunks (float4) ------------
__global__ __launch_bounds__(512) void k_gather(const float* __restrict__ tape,
                                                const int* __restrict__ topk_ws,
                                                const float* __restrict__ weights_ws,
                                                float* __restrict__ partials) {
    const int b = blockIdx.y;
    const int kc = blockIdx.x;
    const int rs = threadIdx.x >> 7;   // 0..3 row-subgroup
    const int f4 = threadIdx.x & 127;  // float4 feature index
    __shared__ float wsh[KPER];
    __shared__ int ish[KPER];
    __shared__ float4 shacc[512];
    if (threadIdx.x < KPER) {
        wsh[threadIdx.x] = weights_ws[b * TOPK + kc * KPER + threadIdx.x];
        ish[threadIdx.x] = topk_ws[b * TOPK + kc * KPER + threadIdx.x];
    }
    __syncthreads();
    float4 acc = {0.f, 0.f, 0.f, 0.f};
#pragma unroll 4
    for (int k = rs; k < KPER; k += 4) {
        const float w = wsh[k];
        const float4 t =
            reinterpret_cast<const float4*>(tape + ((size_t)b * NUM_TAPE + ish[k]) * FEATURES)[f4];
        acc.x = fmaf(w, t.x, acc.x);
        acc.y = fmaf(w, t.y, acc.y);
        acc.z = fmaf(w, t.z, acc.z);
        acc.w = fmaf(w, t.w, acc.w);
    }
    shacc[threadIdx.x] = acc;
    __syncthreads();
    if (threadIdx.x < 128) {
        const float4 a0 = shacc[f4];
        const float4 a1 = shacc[128 + f4];
        const float4 a2 = shacc[256 + f4];
        const float4 a3 = shacc[384 + f4];
        float4 r;
        r.x = (a0.x + a1.x) + (a2.x + a3.x);
        r.y = (a0.y + a1.y) + (a2.y + a3.y);
        r.z = (a0.z + a1.z) + (a2.z + a3.z);
        r.w = (a0.w + a1.w) + (a2.w + a3.w);
        reinterpret_cast<float4*>(partials + ((size_t)b * KCHUNKS + kc) * FEATURES)[f4] = r;
    }
}

// ---------------- Kernel D: reduce partials -> token_sel + query update ------------
__global__ __launch_bounds__(512) void k_finish(const float* __restrict__ q,
                                                const float* __restrict__ partials,
                                                float* __restrict__ out) {
    const int b = blockIdx.x;
    const int g = threadIdx.x >> 7;    // 0..3
    const int f4 = threadIdx.x & 127;  // float4 feature index
    __shared__ float4 sh[512];
    const float4* pp = reinterpret_cast<const float4*>(partials + (size_t)b * KCHUNKS * FEATURES);
    const float4 a = pp[g * 128 + f4];
    const float4 c = pp[(g + 4) * 128 + f4];
    float4 r;
    r.x = a.x + c.x;
    r.y = a.y + c.y;
    r.z = a.z + c.z;
    r.w = a.w + c.w;
    sh[threadIdx.x] = r;
    __syncthreads();
    if (threadIdx.x < 128) {
        const float4 s0 = sh[f4];
        const float4 s1 = sh[128 + f4];
        const float4 s2 = sh[256 + f4];
        const float4 s3 = sh[384 + f4];
        float4 s;
        s.x = (s0.x + s1.x) + (s2.x + s3.x);
        s.y = (s0.y + s1.y) + (s2.y + s3.y);
        s.z = (s0.z + s1.z) + (s2.z + s3.z);
        s.w = (s0.w + s1.w) + (s2.w + s3.w);
        reinterpret_cast<float4*>(out + OFF_TSEL + (size_t)b * FEATURES)[f4] = s;
        if (f4 < 64) {
            const float4 qv = reinterpret_cast<const float4*>(q + (size_t)b * DK)[f4];
            float4 nq;
            nq.x = (qv.x + s.x) * 0.5f;
            nq.y = (qv.y + s.y) * 0.5f;
            nq.z = (qv.z + s.z) * 0.5f;
            nq.w = (qv.w + s.w) * 0.5f;
            reinterpret_cast<float4*>(out + OFF_Q + (size_t)b * DK)[f4] = nq;
        }
    }
}

extern "C" void kernel_launch(void* const* d_in, const int* in_sizes, int n_in,
                              void* d_out, int out_size, void* d_ws, size_t ws_size,
                              hipStream_t stream) {
    const float* q = (const float*)d_in[0];
    const float* hp = (const float*)d_in[1];
    const float* rem = (const float*)d_in[2];
    const float* nup = (const float*)d_in[3];
    const float* mask = (const float*)d_in[4];
    const float* tape = (const float*)d_in[5];
    float* out = (float*)d_out;
    float* ws = (float*)d_ws;

    float* scores = ws + WS_SCORES;
    int* topk = (int*)(ws + WS_TOPK);
    float* weights = ws + WS_WEIGHTS;
    float* partials = ws + WS_PART;

    k_scores<<<dim3(NUM_TAPE / 32, BATCH), 256, 0, stream>>>(q, tape, scores);
    k_topk<<<BATCH, 512, 0, stream>>>(scores, mask, hp, rem, nup, topk, weights, out);
    k_gather<<<dim3(KCHUNKS, BATCH), 512, 0, stream>>>(tape, topk, weights, partials);
    k_finish<<<BATCH, 512, 0, stream>>>(q, partials, out);
}